// Round 4
// baseline (327.583 us; speedup 1.0000x reference)
//
#include <hip/hip_runtime.h>
#include <hip/hip_bf16.h>

#define NL 2
// B=32, K=64, D=256, LS=128, rows = B*K = 2048

using bf16 = __hip_bfloat16;

__device__ __forceinline__ float bfu(unsigned short u) { return __uint_as_float(((unsigned)u) << 16); }

// sigmoid-form gelu for the bulk sweep: x*sigmoid(1.702x), |err| <= ~0.02
__device__ __forceinline__ float gelu_s(float x) {
  float e = __expf(-1.702f * x);
  return x * __builtin_amdgcn_rcpf(1.0f + e);
}

// exact gelu for the low-volume spots (k4 MLP, k5 head)
__device__ __forceinline__ float gelu_e(float x) {
  return 0.5f * x * (1.0f + erff(x * 0.7071067811865475f));
}

// dtype-adaptive input load: fl=1 -> bf16 halfwords, fl=0 -> fp32
__device__ __forceinline__ float load_f(const void* p, int i, int fl) {
  if (fl) return bfu(((const unsigned short*)p)[i]);
  return ((const float*)p)[i];
}

// ---------------------------------------------------------------------------
// detect: view first 256 halfwords of X as bf16; fp32 data shows insane values
// ---------------------------------------------------------------------------
__global__ __launch_bounds__(256) void detect_kernel(const void* __restrict__ X, int* __restrict__ flag) {
  __shared__ int bad;
  if (threadIdx.x == 0) bad = 0;
  __syncthreads();
  const unsigned short h = ((const unsigned short*)X)[threadIdx.x];
  const float v = bfu(h);
  if (!(fabsf(v) < 1e6f)) atomicOr(&bad, 1);
  __syncthreads();
  if (threadIdx.x == 0) *flag = bad ? 0 : 1;    // 1 = inputs are bf16
}

// ---------------------------------------------------------------------------
// prep: inputs -> fp32 in ws (dtype-adaptive)
//   wf  [NL][256 d][1024 n]: n<256 k_w | q_w*scale | Wa+Wb | Wb
//   w3  [NL*3][256 d][256 e]: rv_w2^T, mlp_w1^T, mlp_w2^T
//   wh  : projT [256][128], muT [128][128], spT [128][128]
//   bc  : rb1|rb2|lng|lnb|mb1|mb2 (NL*256 each), pb|mub|spb (128 each)
// ---------------------------------------------------------------------------
__global__ __launch_bounds__(256) void prep_kernel(
    const void* __restrict__ X, const void* __restrict__ kw, const void* __restrict__ qw,
    const void* __restrict__ rw1, const void* __restrict__ rw2, const void* __restrict__ mw1,
    const void* __restrict__ mw2, const void* __restrict__ pw, const void* __restrict__ muw,
    const void* __restrict__ spw,
    const void* __restrict__ rb1, const void* __restrict__ rb2, const void* __restrict__ lng,
    const void* __restrict__ lnb, const void* __restrict__ mb1, const void* __restrict__ mb2,
    const void* __restrict__ pb, const void* __restrict__ mub, const void* __restrict__ spb,
    const int* __restrict__ flag,
    float* __restrict__ x, float* __restrict__ wf, float* __restrict__ w3,
    float* __restrict__ wh, float* __restrict__ bc)
{
  const int fl = *flag;
  int idx = blockIdx.x * 256 + threadIdx.x;
  if (idx < NL * 262144) {
    int l = idx >> 18, rem = idx & 262143;
    int d = rem >> 10, n = rem & 1023;
    int seg = n >> 8, e = n & 255;
    float v;
    if (seg == 0)      v = load_f(kw, (l*256 + e)*256 + d, fl);
    else if (seg == 1) v = load_f(qw, (l*256 + e)*256 + d, fl) * 0.0625f;  // D^-0.5
    else {
      const int rbase = (l*256 + e)*512;
      float wb = load_f(rw1, rbase + 256 + d, fl);
      v = (seg == 2) ? (load_f(rw1, rbase + d, fl) + wb) : wb;
    }
    wf[idx] = v;
    return;
  }
  idx -= NL * 262144;
  if (idx < NL * 3 * 65536) {
    int l3 = idx >> 16, rem = idx & 65535;
    int d = rem >> 8, e = rem & 255;
    int l = l3 / 3, m = l3 % 3;
    const void* src = (m == 0) ? rw2 : (m == 1) ? mw1 : mw2;
    w3[idx] = load_f(src, (l*256 + e)*256 + d, fl);
    return;
  }
  idx -= NL * 3 * 65536;
  if (idx < 65536) {
    if (idx < 32768) {
      int d = idx >> 7, l = idx & 127;
      wh[idx] = load_f(pw, l*256 + d, fl);
    } else if (idx < 49152) {
      int rem = idx - 32768, c = rem >> 7, l = rem & 127;
      wh[idx] = load_f(muw, l*128 + c, fl);
    } else {
      int rem = idx - 49152, c = rem >> 7, l = rem & 127;
      wh[idx] = load_f(spw, l*128 + c, fl);
    }
    return;
  }
  idx -= 65536;
  if (idx < 524288) {
    x[idx] = load_f(X, idx, fl);
    return;
  }
  idx -= 524288;
  if (idx < 3456) {
    const void* src; int off;
    if (idx < 512)       { src = rb1; off = idx; }
    else if (idx < 1024) { src = rb2; off = idx - 512; }
    else if (idx < 1536) { src = lng; off = idx - 1024; }
    else if (idx < 2048) { src = lnb; off = idx - 1536; }
    else if (idx < 2560) { src = mb1; off = idx - 2048; }
    else if (idx < 3072) { src = mb2; off = idx - 2560; }
    else if (idx < 3200) { src = pb;  off = idx - 3072; }
    else if (idx < 3328) { src = mub; off = idx - 3200; }
    else                 { src = spb; off = idx - 3328; }
    bc[idx] = load_f(src, off, fl);
  }
}

// ---------------------------------------------------------------------------
// k1: kqpq[2048][1024] = x[2048][256] @ wf + bias  (k | q*scale | P(+rb1) | Q)
// 64x128 tile per block, 256 blocks, 512 threads. X-tile in LDS.
// thread (tr,tc): 4 rows x 4 cols, float4 weight loads, 16 FMA chains.
// ---------------------------------------------------------------------------
__global__ __launch_bounds__(512, 4) void k1_kqpq(
    const float* __restrict__ x, const float* __restrict__ wf_all,
    const float* __restrict__ bc, float* __restrict__ kqpq, int l)
{
  __shared__ float xs[64*256];   // 64 KB
  const int t = threadIdx.x;
  const int br  = (int)blockIdx.x >> 3;    // 32 row-blocks of 64 rows
  const int bcn = (int)blockIdx.x & 7;     // 8 col-blocks of 128 cols
  const int row0 = br * 64;
  const float* xsrc = x + row0*256;
  for (int i = t; i < 4096; i += 512)
    *(float4*)&xs[i*4] = *(const float4*)&xsrc[i*4];
  __syncthreads();

  const int tr = t >> 5, tc = t & 31;      // 16 row-groups x 32 col-groups
  const int n0 = bcn*128 + tc*4;
  const float* w = wf_all + l*262144;
  float4 bv = make_float4(0.f, 0.f, 0.f, 0.f);
  if (n0 >= 512 && n0 < 768) {   // P segment gets rb1 (wave-uniform branch)
    const float* rb1c = bc + l*256 + (n0 - 512);
    bv = make_float4(rb1c[0], rb1c[1], rb1c[2], rb1c[3]);
  }
  float4 acc[4];
  #pragma unroll
  for (int r = 0; r < 4; ++r) acc[r] = bv;

  for (int d0 = 0; d0 < 256; d0 += 4) {
    float4 wv[4];
    #pragma unroll
    for (int dd = 0; dd < 4; ++dd) wv[dd] = *(const float4*)&w[(d0 + dd)*1024 + n0];
    #pragma unroll
    for (int r = 0; r < 4; ++r) {
      const float4 xv = *(const float4*)&xs[(tr*4 + r)*256 + d0];
      acc[r].x = fmaf(xv.x, wv[0].x, acc[r].x);
      acc[r].y = fmaf(xv.x, wv[0].y, acc[r].y);
      acc[r].z = fmaf(xv.x, wv[0].z, acc[r].z);
      acc[r].w = fmaf(xv.x, wv[0].w, acc[r].w);
      acc[r].x = fmaf(xv.y, wv[1].x, acc[r].x);
      acc[r].y = fmaf(xv.y, wv[1].y, acc[r].y);
      acc[r].z = fmaf(xv.y, wv[1].z, acc[r].z);
      acc[r].w = fmaf(xv.y, wv[1].w, acc[r].w);
      acc[r].x = fmaf(xv.z, wv[2].x, acc[r].x);
      acc[r].y = fmaf(xv.z, wv[2].y, acc[r].y);
      acc[r].z = fmaf(xv.z, wv[2].z, acc[r].z);
      acc[r].w = fmaf(xv.z, wv[2].w, acc[r].w);
      acc[r].x = fmaf(xv.w, wv[3].x, acc[r].x);
      acc[r].y = fmaf(xv.w, wv[3].y, acc[r].y);
      acc[r].z = fmaf(xv.w, wv[3].z, acc[r].z);
      acc[r].w = fmaf(xv.w, wv[3].w, acc[r].w);
    }
  }
  #pragma unroll
  for (int r = 0; r < 4; ++r)
    *(float4*)&kqpq[(row0 + tr*4 + r)*1024 + n0] = acc[r];
}

// ---------------------------------------------------------------------------
// k23: block = (b, i-quartet): 4 rows. 512 threads, 512 blocks (2/CU).
// scores: wave-per-(row,j-half), lane-per-d, coalesced global k reads, 64-lane
// butterfly. softmax per row. agg: thread=(row-pair, col), sigmoid-gelu sweep.
// ---------------------------------------------------------------------------
__global__ __launch_bounds__(512, 4) void k23_attn_agg(
    const float* __restrict__ kqpq, float* __restrict__ g)
{
  __shared__ float qs[4][256];
  __shared__ float sc[4][64];
  __shared__ float aa[4][64];
  const int t = threadIdx.x;
  const int b = (int)blockIdx.x >> 4;
  const int qd = (int)blockIdx.x & 15;
  const int base = b << 6, i0 = qd*4;

  for (int i = t; i < 1024; i += 512)
    qs[i >> 8][i & 255] = kqpq[(base + i0 + (i >> 8))*1024 + 256 + (i & 255)];
  __syncthreads();

  // scores: wave w -> row r=w&3, j-half jh=w>>2; lane = d-quad
  {
    const int w = t >> 6, lane = t & 63;
    const int r = w & 3, jh = w >> 2;
    const float4 qv = ((const float4*)&qs[r][0])[lane];
    for (int jj = 0; jj < 32; ++jj) {
      const int j = jh*32 + jj;
      const float4 kv = ((const float4*)(kqpq + (base + j)*1024))[lane];
      float s = kv.x*qv.x;
      s = fmaf(kv.y, qv.y, s);
      s = fmaf(kv.z, qv.z, s);
      s = fmaf(kv.w, qv.w, s);
      #pragma unroll
      for (int off = 32; off; off >>= 1) s += __shfl_xor(s, off, 64);
      if (lane == 0) sc[r][j] = s;
    }
  }
  __syncthreads();
  if (t < 256) {
    const int r = t >> 6, j = t & 63;
    float s = sc[r][j];
    float m = s;
    #pragma unroll
    for (int off = 32; off; off >>= 1) m = fmaxf(m, __shfl_xor(m, off, 64));
    const float e = __expf(s - m);
    float ssum = e;
    #pragma unroll
    for (int off = 32; off; off >>= 1) ssum += __shfl_xor(ssum, off, 64);
    aa[r][j] = e / ssum;
  }
  __syncthreads();

  // aggregation: thread = (row-pair rh, col); rows i0+rh*2, i0+rh*2+1
  const int rh = t >> 8, col = t & 255;
  const int r0 = i0 + rh*2;
  const float p0 = kqpq[(base + r0    )*1024 + 512 + col];
  const float p1 = kqpq[(base + r0 + 1)*1024 + 512 + col];
  float a0 = 0.f, a1 = 0.f;
  for (int j = 0; j < 64; ++j) {
    const float qv = kqpq[(base + j)*1024 + 768 + col];
    const float w0 = aa[rh*2][j], w1 = aa[rh*2 + 1][j];
    a0 = fmaf(w0, gelu_s(p0 - qv), a0);
    a1 = fmaf(w1, gelu_s(p1 - qv), a1);
  }
  g[(base + r0    )*256 + col] = a0;
  g[(base + r0 + 1)*256 + col] = a1;
}

// ---------------------------------------------------------------------------
// k4: agg = g@rw2^T+rb2 ; h=LN(x+agg) ; x += mlp2(gelu(mlp1(h)))   (in-place)
// 8 rows/block, 256 blocks, 1024 threads (16 waves/CU).
// thread = (ds: d-half, rg: 2-row group, ch: 2 cols); partials combined in LDS.
// ---------------------------------------------------------------------------
__device__ __forceinline__ void k4_gemm(
    const float* src /*LDS 8x256*/, const float* __restrict__ wl,
    float* part /*LDS [2][8][256]*/, int ds, int rg, int ch)
{
  const int dbase = ds*128;
  const int e0 = ch*2;
  float a00 = 0.f, a01 = 0.f, a10 = 0.f, a11 = 0.f;
  const float* s0p = src + (rg*2    )*256 + dbase;
  const float* s1p = src + (rg*2 + 1)*256 + dbase;
  for (int d0 = 0; d0 < 128; d0 += 4) {
    const float4 s0v = *(const float4*)&s0p[d0];
    const float4 s1v = *(const float4*)&s1p[d0];
    float2 wv;
    wv = *(const float2*)&wl[(dbase + d0    )*256 + e0];
    a00 = fmaf(s0v.x, wv.x, a00); a01 = fmaf(s0v.x, wv.y, a01);
    a10 = fmaf(s1v.x, wv.x, a10); a11 = fmaf(s1v.x, wv.y, a11);
    wv = *(const float2*)&wl[(dbase + d0 + 1)*256 + e0];
    a00 = fmaf(s0v.y, wv.x, a00); a01 = fmaf(s0v.y, wv.y, a01);
    a10 = fmaf(s1v.y, wv.x, a10); a11 = fmaf(s1v.y, wv.y, a11);
    wv = *(const float2*)&wl[(dbase + d0 + 2)*256 + e0];
    a00 = fmaf(s0v.z, wv.x, a00); a01 = fmaf(s0v.z, wv.y, a01);
    a10 = fmaf(s1v.z, wv.x, a10); a11 = fmaf(s1v.z, wv.y, a11);
    wv = *(const float2*)&wl[(dbase + d0 + 3)*256 + e0];
    a00 = fmaf(s0v.w, wv.x, a00); a01 = fmaf(s0v.w, wv.y, a01);
    a10 = fmaf(s1v.w, wv.x, a10); a11 = fmaf(s1v.w, wv.y, a11);
  }
  *(float2*)&part[ds*2048 + (rg*2    )*256 + e0] = make_float2(a00, a01);
  *(float2*)&part[ds*2048 + (rg*2 + 1)*256 + e0] = make_float2(a10, a11);
}

__global__ __launch_bounds__(1024, 4) void k4_mix(
    const float* __restrict__ g, const float* __restrict__ w3,
    const float* __restrict__ bc, float* __restrict__ x, int l)
{
  __shared__ float xt[2048];
  __shared__ float bufA[2048];
  __shared__ float bufB[2048];
  __shared__ float part[2*2048];
  __shared__ float mv[8][2];
  const int t = threadIdx.x;
  const int row0 = blockIdx.x * 8;
  if (t < 512) {
    *(float4*)&xt[t*4]   = *(const float4*)&x[row0*256 + t*4];
    *(float4*)&bufA[t*4] = *(const float4*)&g[row0*256 + t*4];
  }
  __syncthreads();
  // thread decomposition: ds = t>>9, rg = (t>>7)&3, ch = t&127 (wave-uniform ds,rg)
  const int ds = t >> 9, rg = (t >> 7) & 3, ch = t & 127;
  const int i1 = t, i2 = t + 1024;           // reduce-phase element indices
  const int c1 = i1 & 255, c2 = i2 & 255;
  const float* wl = w3 + l*3*65536;
  const float* rb2c = bc + 512  + l*256;
  const float* lngc = bc + 1024 + l*256;
  const float* lnbc = bc + 1536 + l*256;
  const float* mb1c = bc + 2048 + l*256;
  const float* mb2c = bc + 2560 + l*256;

  // ---- gemm1: agg = bufA @ rw2^T + rb2 ; bufB = xt + agg
  k4_gemm(bufA, wl, part, ds, rg, ch);
  __syncthreads();
  bufB[i1] = xt[i1] + part[i1] + part[2048 + i1] + rb2c[c1];
  bufB[i2] = xt[i2] + part[i2] + part[2048 + i2] + rb2c[c2];
  __syncthreads();
  // ---- LN stats (rows 8, 64 lanes each)
  if (t < 512) {
    const int row = t >> 6, lane = t & 63;
    float s = 0.f, s2 = 0.f;
    #pragma unroll
    for (int kk = 0; kk < 4; ++kk) {
      const float v = bufB[row*256 + lane + kk*64];
      s += v; s2 = fmaf(v, v, s2);
    }
    #pragma unroll
    for (int off = 32; off; off >>= 1) {
      s  += __shfl_xor(s, off, 64);
      s2 += __shfl_xor(s2, off, 64);
    }
    if (lane == 0) {
      const float mu = s * (1.f/256.f);
      mv[row][0] = mu;
      mv[row][1] = rsqrtf(fmaf(-mu, mu, s2 * (1.f/256.f)) + 1e-5f);
    }
  }
  __syncthreads();
  // ---- LN apply
  {
    const int r1 = i1 >> 8, r2 = i2 >> 8;
    bufB[i1] = (bufB[i1] - mv[r1][0]) * mv[r1][1] * lngc[c1] + lnbc[c1];
    bufB[i2] = (bufB[i2] - mv[r2][0]) * mv[r2][1] * lngc[c2] + lnbc[c2];
  }
  __syncthreads();
  // ---- gemm2 + gelu
  k4_gemm(bufB, wl + 65536, part, ds, rg, ch);
  __syncthreads();
  bufA[i1] = gelu_e(part[i1] + part[2048 + i1] + mb1c[c1]);
  bufA[i2] = gelu_e(part[i2] + part[2048 + i2] + mb1c[c2]);
  __syncthreads();
  // ---- gemm3 + residual -> x
  k4_gemm(bufA, wl + 2*65536, part, ds, rg, ch);
  __syncthreads();
  x[row0*256 + i1] = xt[i1] + part[i1] + part[2048 + i1] + mb2c[c1];
  x[row0*256 + i2] = xt[i2] + part[i2] + part[2048 + i2] + mb2c[c2];
}

// ---------------------------------------------------------------------------
// k5: s=sum_K x ; h=gelu(s@projT+pb) ; mu=h@muT+mb ; scale=softplus(h@spT+sb)
// ---------------------------------------------------------------------------
__global__ __launch_bounds__(256) void k5_head(
    const float* __restrict__ x, const float* __restrict__ wh,
    const float* __restrict__ bc, const int* __restrict__ flag,
    void* __restrict__ out)
{
  __shared__ float ss[256];
  __shared__ float hh[128];
  const int b = blockIdx.x, t = threadIdx.x;
  const int fl = *flag;
  float s = 0.f;
  for (int i = 0; i < 64; ++i) s += x[((b << 6) + i)*256 + t];
  ss[t] = s;
  __syncthreads();
  if (t < 128) {
    float acc = bc[3072 + t];
    const float* projT = wh;
    for (int d = 0; d < 256; ++d) acc = fmaf(ss[d], projT[d*128 + t], acc);
    hh[t] = gelu_e(acc);
  }
  __syncthreads();
  float v; int oidx;
  if (t < 128) {
    float acc = bc[3200 + t];
    const float* muT = wh + 32768;
    for (int c = 0; c < 128; ++c) acc = fmaf(hh[c], muT[c*128 + t], acc);
    v = acc; oidx = b*128 + t;
  } else {
    const int u = t - 128;
    float acc = bc[3328 + u];
    const float* spT = wh + 49152;
    for (int c = 0; c < 128; ++c) acc = fmaf(hh[c], spT[c*128 + u], acc);
    v = (acc > 20.f) ? acc : log1pf(__expf(acc));
    oidx = 4096 + b*128 + u;
  }
  if (fl) ((bf16*)out)[oidx] = __float2bfloat16(v);
  else    ((float*)out)[oidx] = v;
}

// ---------------------------------------------------------------------------
extern "C" void kernel_launch(void* const* d_in, const int* in_sizes, int n_in,
                              void* d_out, int out_size, void* d_ws, size_t ws_size,
                              hipStream_t stream)
{
  (void)in_sizes; (void)n_in; (void)out_size; (void)ws_size;
  float* ws    = (float*)d_ws;
  int*   flag  = (int*)ws;                // [16 floats reserved]
  float* x     = ws + 16;                 // 524288
  float* kqpq  = x + 524288;              // 2097152
  float* g     = kqpq + 2097152;          // 524288
  float* wf    = g + 524288;              // NL*262144 = 524288
  float* w3    = wf + 524288;             // NL*3*65536 = 393216
  float* wh    = w3 + 393216;             // 65536
  float* bc    = wh + 65536;              // 3456

  detect_kernel<<<dim3(1), dim3(256), 0, stream>>>(d_in[0], flag);
  prep_kernel<<<dim3(5902), dim3(256), 0, stream>>>(
      d_in[0], d_in[1], d_in[2], d_in[3], d_in[5], d_in[9], d_in[11],
      d_in[13], d_in[15], d_in[17],
      d_in[4], d_in[6], d_in[7], d_in[8], d_in[10], d_in[12],
      d_in[14], d_in[16], d_in[18],
      flag, x, wf, w3, wh, bc);
  for (int l = 0; l < NL; ++l) {
    k1_kqpq<<<dim3(256), dim3(512), 0, stream>>>(x, wf, bc, kqpq, l);
    k23_attn_agg<<<dim3(512), dim3(512), 0, stream>>>(kqpq, g);
    k4_mix<<<dim3(256), dim3(1024), 0, stream>>>(g, w3, bc, x, l);
  }
  k5_head<<<dim3(32), dim3(256), 0, stream>>>(x, wh, bc, flag, (void*)d_out);
}

// Round 5
// 237.191 us; speedup vs baseline: 1.3811x; 1.3811x over previous
//
#include <hip/hip_runtime.h>
#include <hip/hip_bf16.h>

#define NL 2
// B=32, K=64, D=256, LS=128, rows = B*K = 2048

using bf16 = __hip_bfloat16;
typedef short bf16x8 __attribute__((ext_vector_type(8)));
typedef float f32x4 __attribute__((ext_vector_type(4)));

__device__ __forceinline__ float bfu(unsigned short u) { return __uint_as_float(((unsigned)u) << 16); }

__device__ __forceinline__ unsigned short bfr(float v) {   // RNE fp32->bf16 bits
  unsigned u = __float_as_uint(v);
  u += 0x7FFFu + ((u >> 16) & 1u);
  return (unsigned short)(u >> 16);
}

// sigmoid-form gelu for the bulk sweep: x*sigmoid(1.702x)
__device__ __forceinline__ float gelu_s(float x) {
  float e = __expf(-1.702f * x);
  return x * __builtin_amdgcn_rcpf(1.0f + e);
}

// exact gelu for the low-volume spots
__device__ __forceinline__ float gelu_e(float x) {
  return 0.5f * x * (1.0f + erff(x * 0.7071067811865475f));
}

__device__ __forceinline__ float load_f(const void* p, int i, int fl) {
  if (fl) return bfu(((const unsigned short*)p)[i]);
  return ((const float*)p)[i];
}

// split fp32x8 into bf16 hi + lo fragments
__device__ __forceinline__ void split8(const float4 v0, const float4 v1, bf16x8& hi, bf16x8& lo) {
  float vs[8] = {v0.x, v0.y, v0.z, v0.w, v1.x, v1.y, v1.z, v1.w};
  #pragma unroll
  for (int i = 0; i < 8; ++i) {
    unsigned short h = bfr(vs[i]);
    hi[i] = (short)h;
    lo[i] = (short)bfr(vs[i] - bfu(h));
  }
}

// ---------------------------------------------------------------------------
__global__ __launch_bounds__(256) void detect_kernel(const void* __restrict__ X, int* __restrict__ flag) {
  __shared__ int bad;
  if (threadIdx.x == 0) bad = 0;
  __syncthreads();
  const unsigned short h = ((const unsigned short*)X)[threadIdx.x];
  const float v = bfu(h);
  if (!(fabsf(v) < 1e6f)) atomicOr(&bad, 1);
  __syncthreads();
  if (threadIdx.x == 0) *flag = bad ? 0 : 1;    // 1 = inputs are bf16
}

// ---------------------------------------------------------------------------
// prep: inputs -> ws
//  wfb (bf16, MFMA B-frag order): [l][kt8][nt64][lane64][j8]
//      n = nt*16+(lane&15): n<256 k_w | q_w*0.0625 | Wa+Wb | Wb ; d = kt*32+((lane>>4)&3)*8+j
//  w3b (bf16, B-frag order): [l][gm3][kt8][nt16][lane64][j8], gm: rv_w2,mlp_w1,mlp_w2 (e=nt*16+(lane&15), d as above)
//  wh fp32: projT [256][128], muT [128][128], spT [128][128]
//  x fp32 [2048][256]; bc fp32 biases
// ---------------------------------------------------------------------------
__global__ __launch_bounds__(256) void prep_kernel(
    const void* __restrict__ X, const void* __restrict__ kw, const void* __restrict__ qw,
    const void* __restrict__ rw1, const void* __restrict__ rw2, const void* __restrict__ mw1,
    const void* __restrict__ mw2, const void* __restrict__ pw, const void* __restrict__ muw,
    const void* __restrict__ spw,
    const void* __restrict__ rb1, const void* __restrict__ rb2, const void* __restrict__ lng,
    const void* __restrict__ lnb, const void* __restrict__ mb1, const void* __restrict__ mb2,
    const void* __restrict__ pb, const void* __restrict__ mub, const void* __restrict__ spb,
    const int* __restrict__ flag,
    float* __restrict__ x, unsigned short* __restrict__ wfb, unsigned short* __restrict__ w3b,
    float* __restrict__ wh, float* __restrict__ bc)
{
  const int fl = *flag;
  int idx = blockIdx.x * 256 + threadIdx.x;
  if (idx < 524288) {           // wfb
    const int j = idx & 7, lane = (idx >> 3) & 63, nt = (idx >> 9) & 63;
    const int kt = (idx >> 15) & 7, l = idx >> 18;
    const int d = kt*32 + ((lane >> 4) & 3)*8 + j;
    const int n = nt*16 + (lane & 15);
    const int seg = n >> 8, e = n & 255;
    float v;
    if (seg == 0)      v = load_f(kw, (l*256 + e)*256 + d, fl);
    else if (seg == 1) v = load_f(qw, (l*256 + e)*256 + d, fl) * 0.0625f;
    else {
      const int rbase = (l*256 + e)*512;
      float wb = load_f(rw1, rbase + 256 + d, fl);
      v = (seg == 2) ? (load_f(rw1, rbase + d, fl) + wb) : wb;
    }
    wfb[idx] = bfr(v);
    return;
  }
  idx -= 524288;
  if (idx < 393216) {           // w3b
    const int j = idx & 7, lane = (idx >> 3) & 63, nt = (idx >> 9) & 15;
    const int kt = (idx >> 13) & 7, g3 = idx >> 16;
    const int l = g3 / 3, gm = g3 % 3;
    const int d = kt*32 + ((lane >> 4) & 3)*8 + j;
    const int e = nt*16 + (lane & 15);
    const void* src = (gm == 0) ? rw2 : (gm == 1) ? mw1 : mw2;
    w3b[idx] = bfr(load_f(src, (l*256 + e)*256 + d, fl));
    return;
  }
  idx -= 393216;
  if (idx < 65536) {            // wh
    if (idx < 32768) {
      int d = idx >> 7, l = idx & 127;
      wh[idx] = load_f(pw, l*256 + d, fl);
    } else if (idx < 49152) {
      int rem = idx - 32768, c = rem >> 7, l = rem & 127;
      wh[idx] = load_f(muw, l*128 + c, fl);
    } else {
      int rem = idx - 49152, c = rem >> 7, l = rem & 127;
      wh[idx] = load_f(spw, l*128 + c, fl);
    }
    return;
  }
  idx -= 65536;
  if (idx < 524288) {           // x
    x[idx] = load_f(X, idx, fl);
    return;
  }
  idx -= 524288;
  if (idx < 3456) {             // bc
    const void* src; int off;
    if (idx < 512)       { src = rb1; off = idx; }
    else if (idx < 1024) { src = rb2; off = idx - 512; }
    else if (idx < 1536) { src = lng; off = idx - 1024; }
    else if (idx < 2048) { src = lnb; off = idx - 1536; }
    else if (idx < 2560) { src = mb1; off = idx - 2048; }
    else if (idx < 3072) { src = mb2; off = idx - 2560; }
    else if (idx < 3200) { src = pb;  off = idx - 3072; }
    else if (idx < 3328) { src = mub; off = idx - 3200; }
    else                 { src = spb; off = idx - 3328; }
    bc[idx] = load_f(src, off, fl);
  }
}

// ---------------------------------------------------------------------------
// k1: kqpq[2048][1024] = x @ W (MFMA, split-A bf16, exact-bf16 weights)
// block: 256 thr / 4 waves, tile M=16 x N=512; grid (128 m) x (2 n)
// ---------------------------------------------------------------------------
__global__ __launch_bounds__(256) void k1_kqpq(
    const float* __restrict__ x, const unsigned short* __restrict__ wfb,
    const float* __restrict__ bc, float* __restrict__ kqpq, int l)
{
  __shared__ __align__(16) unsigned short aF[2][4096];   // [hi/lo][kt*512 + lane*8 + j]
  const int t = threadIdx.x;
  const int mb = (int)blockIdx.x >> 1, nb = (int)blockIdx.x & 1;
  const int row0 = mb * 16;
  // stage A (16 rows x 256 d fp32 -> hi/lo bf16 frags)
  #pragma unroll
  for (int i = 0; i < 4; ++i) {
    const int c = t + i*256;                 // 1024 chunks of 4 floats
    const int row = c >> 6, d0 = (c & 63)*4;
    const float4 v = *(const float4*)&x[(row0 + row)*256 + d0];
    ushort4 h, lo;
    h.x = bfr(v.x); h.y = bfr(v.y); h.z = bfr(v.z); h.w = bfr(v.w);
    lo.x = bfr(v.x - bfu(h.x)); lo.y = bfr(v.y - bfu(h.y));
    lo.z = bfr(v.z - bfu(h.z)); lo.w = bfr(v.w - bfu(h.w));
    const int kt = d0 >> 5;
    const int lane = row | (((d0 >> 3) & 3) << 4);
    const int j = d0 & 7;
    *(ushort4*)&aF[0][kt*512 + lane*8 + j] = h;
    *(ushort4*)&aF[1][kt*512 + lane*8 + j] = lo;
  }
  __syncthreads();

  const int w = t >> 6, l64 = t & 63;
  const int col = l64 & 15, quad = l64 >> 4;
  f32x4 acc[8];
  #pragma unroll
  for (int i = 0; i < 8; ++i) acc[i] = (f32x4){0.f, 0.f, 0.f, 0.f};

  for (int kt = 0; kt < 8; ++kt) {
    const bf16x8 ah = *(const bf16x8*)&aF[0][kt*512 + l64*8];
    const bf16x8 al = *(const bf16x8*)&aF[1][kt*512 + l64*8];
    #pragma unroll
    for (int i = 0; i < 8; ++i) {
      const int ntg = nb*32 + w*8 + i;
      const bf16x8 b = *(const bf16x8*)&wfb[((l*8 + kt)*64 + ntg)*512 + l64*8];
      acc[i] = __builtin_amdgcn_mfma_f32_16x16x32_bf16(ah, b, acc[i], 0, 0, 0);
      acc[i] = __builtin_amdgcn_mfma_f32_16x16x32_bf16(al, b, acc[i], 0, 0, 0);
    }
  }
  #pragma unroll
  for (int i = 0; i < 8; ++i) {
    const int ntg = nb*32 + w*8 + i;
    const int n = ntg*16 + col;
    const float bias = (ntg >= 32 && ntg < 48) ? bc[l*256 + (n - 512)] : 0.f;
    #pragma unroll
    for (int r = 0; r < 4; ++r)
      kqpq[(row0 + quad*4 + r)*1024 + n] = acc[i][r] + bias;
  }
}

// ---------------------------------------------------------------------------
// ks: per-b scores S = q @ k^T (split-bf16 MFMA, 3 terms) -> softmax -> attn
// grid 32, 256 thr / 4 waves; wave w = m-tile w, n-tiles 0..3
// ---------------------------------------------------------------------------
__global__ __launch_bounds__(256) void ks_scores(
    const float* __restrict__ kqpq, float* __restrict__ attn)
{
  __shared__ float S[64*68];
  __shared__ float mrow[64], srow[64];
  const int b = blockIdx.x, base = b << 6;
  const int t = threadIdx.x, w = t >> 6, l64 = t & 63;
  const int col = l64 & 15, quad = l64 >> 4;

  f32x4 acc[4];
  #pragma unroll
  for (int i = 0; i < 4; ++i) acc[i] = (f32x4){0.f, 0.f, 0.f, 0.f};

  const float* qrow = kqpq + (base + w*16 + col)*1024 + 256;   // q segment, row = m
  for (int kt = 0; kt < 8; ++kt) {
    const int doff = kt*32 + quad*8;
    bf16x8 ah, al;
    split8(*(const float4*)&qrow[doff], *(const float4*)&qrow[doff + 4], ah, al);
    #pragma unroll
    for (int nt = 0; nt < 4; ++nt) {
      const float* krow = kqpq + (base + nt*16 + col)*1024;    // k segment, row = n
      bf16x8 bh, bl;
      split8(*(const float4*)&krow[doff], *(const float4*)&krow[doff + 4], bh, bl);
      acc[nt] = __builtin_amdgcn_mfma_f32_16x16x32_bf16(ah, bh, acc[nt], 0, 0, 0);
      acc[nt] = __builtin_amdgcn_mfma_f32_16x16x32_bf16(ah, bl, acc[nt], 0, 0, 0);
      acc[nt] = __builtin_amdgcn_mfma_f32_16x16x32_bf16(al, bh, acc[nt], 0, 0, 0);
    }
  }
  #pragma unroll
  for (int nt = 0; nt < 4; ++nt)
    #pragma unroll
    for (int r = 0; r < 4; ++r)
      S[(w*16 + quad*4 + r)*68 + nt*16 + col] = acc[nt][r];
  __syncthreads();
  {
    const int row = t >> 2, part = t & 3;
    float m = -1e30f;
    for (int c = part*16; c < part*16 + 16; ++c) m = fmaxf(m, S[row*68 + c]);
    m = fmaxf(m, __shfl_xor(m, 1, 64));
    m = fmaxf(m, __shfl_xor(m, 2, 64));
    float s = 0.f;
    for (int c = part*16; c < part*16 + 16; ++c) s += __expf(S[row*68 + c] - m);
    s += __shfl_xor(s, 1, 64);
    s += __shfl_xor(s, 2, 64);
    if (part == 0) { mrow[row] = m; srow[row] = 1.f / s; }
  }
  __syncthreads();
  #pragma unroll
  for (int i = 0; i < 16; ++i) {
    const int idx = i*256 + t;
    const int row = idx >> 6, c = idx & 63;
    attn[b*4096 + idx] = __expf(S[row*68 + c] - mrow[row]) * srow[row];
  }
}

// ---------------------------------------------------------------------------
// k23_agg: g[b,i,:] = sum_j attn[b,i,j] * gelu(P_i - Q_j)
// 512 blocks x 512 thr: block = (b, i-quartet); thread = (row-pair, col)
// ---------------------------------------------------------------------------
__global__ __launch_bounds__(512) void k23_agg(
    const float* __restrict__ kqpq, const float* __restrict__ attn, float* __restrict__ g)
{
  __shared__ float aa[4][64];
  const int t = threadIdx.x;
  const int b = (int)blockIdx.x >> 4;
  const int qd = (int)blockIdx.x & 15;
  const int base = b << 6, i0 = qd*4;
  if (t < 256) aa[t >> 6][t & 63] = attn[b*4096 + (i0 + (t >> 6))*64 + (t & 63)];
  __syncthreads();

  const int rh = t >> 8, col = t & 255;
  const int r0 = i0 + rh*2;
  const float p0 = kqpq[(base + r0    )*1024 + 512 + col];
  const float p1 = kqpq[(base + r0 + 1)*1024 + 512 + col];
  float a0 = 0.f, a1 = 0.f;
  for (int j = 0; j < 64; ++j) {
    const float qv = kqpq[(base + j)*1024 + 768 + col];
    const float w0 = aa[rh*2][j], w1 = aa[rh*2 + 1][j];
    a0 = fmaf(w0, gelu_s(p0 - qv), a0);
    a1 = fmaf(w1, gelu_s(p1 - qv), a1);
  }
  g[(base + r0    )*256 + col] = a0;
  g[(base + r0 + 1)*256 + col] = a1;
}

// ---------------------------------------------------------------------------
// k4: agg=g@rw2^T+rb2 ; h=LN(x+agg) ; x += mlp2(gelu(mlp1(h)))  (MFMA, 16 rows/block)
// 128 blocks x 256 thr / 4 waves; wave w owns n-tiles w*4..w*4+3
// ---------------------------------------------------------------------------
__device__ __forceinline__ void k4_gemm(
    f32x4 acc[4], const unsigned short aF[2][4096],
    const unsigned short* __restrict__ wg, int w, int l64)
{
  #pragma unroll
  for (int nt = 0; nt < 4; ++nt) acc[nt] = (f32x4){0.f, 0.f, 0.f, 0.f};
  for (int kt = 0; kt < 8; ++kt) {
    const bf16x8 ah = *(const bf16x8*)&aF[0][kt*512 + l64*8];
    const bf16x8 al = *(const bf16x8*)&aF[1][kt*512 + l64*8];
    #pragma unroll
    for (int nt = 0; nt < 4; ++nt) {
      const bf16x8 b = *(const bf16x8*)&wg[((kt*16 + (w*4 + nt))*64 + l64)*8];
      acc[nt] = __builtin_amdgcn_mfma_f32_16x16x32_bf16(ah, b, acc[nt], 0, 0, 0);
      acc[nt] = __builtin_amdgcn_mfma_f32_16x16x32_bf16(al, b, acc[nt], 0, 0, 0);
    }
  }
}

__global__ __launch_bounds__(256) void k4_mix(
    const float* __restrict__ g, const unsigned short* __restrict__ w3b,
    const float* __restrict__ bc, float* __restrict__ x, int l)
{
  __shared__ __align__(16) unsigned short aF[2][4096];
  __shared__ float bufB[16*260];
  __shared__ float mv[16][2];
  const int t = threadIdx.x;
  const int row0 = blockIdx.x * 16;
  const int w = t >> 6, l64 = t & 63;
  const int col = l64 & 15, quad = l64 >> 4;
  const float* rb2c = bc + 512  + l*256;
  const float* lngc = bc + 1024 + l*256;
  const float* lnbc = bc + 1536 + l*256;
  const float* mb1c = bc + 2048 + l*256;
  const float* mb2c = bc + 2560 + l*256;
  const unsigned short* wg = w3b + l*3*65536;

  // x tile in registers (C-layout positions)
  float xtr[4][4];
  #pragma unroll
  for (int nt = 0; nt < 4; ++nt)
    #pragma unroll
    for (int r = 0; r < 4; ++r)
      xtr[nt][r] = x[(row0 + quad*4 + r)*256 + (w*4 + nt)*16 + col];

  // stage g -> hi/lo A-frags
  #pragma unroll
  for (int i = 0; i < 4; ++i) {
    const int c = t + i*256;
    const int row = c >> 6, d0 = (c & 63)*4;
    const float4 v = *(const float4*)&g[(row0 + row)*256 + d0];
    ushort4 h, lo;
    h.x = bfr(v.x); h.y = bfr(v.y); h.z = bfr(v.z); h.w = bfr(v.w);
    lo.x = bfr(v.x - bfu(h.x)); lo.y = bfr(v.y - bfu(h.y));
    lo.z = bfr(v.z - bfu(h.z)); lo.w = bfr(v.w - bfu(h.w));
    const int kt = d0 >> 5, lane = row | (((d0 >> 3) & 3) << 4), j = d0 & 7;
    *(ushort4*)&aF[0][kt*512 + lane*8 + j] = h;
    *(ushort4*)&aF[1][kt*512 + lane*8 + j] = lo;
  }
  __syncthreads();

  f32x4 acc[4];
  // ---- GEMM1: agg -> bufB = x + agg + rb2
  k4_gemm(acc, aF, wg, w, l64);
  #pragma unroll
  for (int nt = 0; nt < 4; ++nt) {
    const int cn = (w*4 + nt)*16 + col;
    #pragma unroll
    for (int r = 0; r < 4; ++r)
      bufB[(quad*4 + r)*260 + cn] = acc[nt][r] + rb2c[cn] + xtr[nt][r];
  }
  __syncthreads();
  // ---- LN stats
  {
    const int row = t >> 4, part = t & 15;
    float s = 0.f, s2 = 0.f;
    #pragma unroll
    for (int kk = 0; kk < 16; ++kk) {
      const float v = bufB[row*260 + part + kk*16];
      s += v; s2 = fmaf(v, v, s2);
    }
    #pragma unroll
    for (int off = 8; off; off >>= 1) {
      s  += __shfl_xor(s, off, 16);
      s2 += __shfl_xor(s2, off, 16);
    }
    if (part == 0) {
      const float mu = s * (1.f/256.f);
      mv[row][0] = mu;
      mv[row][1] = rsqrtf(fmaf(-mu, mu, s2 * (1.f/256.f)) + 1e-5f);
    }
  }
  __syncthreads();
  // ---- LN apply + restage frags
  #pragma unroll
  for (int i = 0; i < 4; ++i) {
    const int c = t + i*256;
    const int row = c >> 6, d0 = (c & 63)*4;
    float4 v = *(const float4*)&bufB[row*260 + d0];
    const float m = mv[row][0], iv = mv[row][1];
    v.x = (v.x - m)*iv*lngc[d0]   + lnbc[d0];
    v.y = (v.y - m)*iv*lngc[d0+1] + lnbc[d0+1];
    v.z = (v.z - m)*iv*lngc[d0+2] + lnbc[d0+2];
    v.w = (v.w - m)*iv*lngc[d0+3] + lnbc[d0+3];
    ushort4 h, lo;
    h.x = bfr(v.x); h.y = bfr(v.y); h.z = bfr(v.z); h.w = bfr(v.w);
    lo.x = bfr(v.x - bfu(h.x)); lo.y = bfr(v.y - bfu(h.y));
    lo.z = bfr(v.z - bfu(h.z)); lo.w = bfr(v.w - bfu(h.w));
    const int kt = d0 >> 5, lane = row | (((d0 >> 3) & 3) << 4), j = d0 & 7;
    *(ushort4*)&aF[0][kt*512 + lane*8 + j] = h;
    *(ushort4*)&aF[1][kt*512 + lane*8 + j] = lo;
  }
  __syncthreads();
  // ---- GEMM2 + gelu -> bufB
  k4_gemm(acc, aF, wg + 65536, w, l64);
  #pragma unroll
  for (int nt = 0; nt < 4; ++nt) {
    const int cn = (w*4 + nt)*16 + col;
    #pragma unroll
    for (int r = 0; r < 4; ++r)
      bufB[(quad*4 + r)*260 + cn] = gelu_e(acc[nt][r] + mb1c[cn]);
  }
  __syncthreads();
  // ---- restage frags from bufB
  #pragma unroll
  for (int i = 0; i < 4; ++i) {
    const int c = t + i*256;
    const int row = c >> 6, d0 = (c & 63)*4;
    const float4 v = *(const float4*)&bufB[row*260 + d0];
    ushort4 h, lo;
    h.x = bfr(v.x); h.y = bfr(v.y); h.z = bfr(v.z); h.w = bfr(v.w);
    lo.x = bfr(v.x - bfu(h.x)); lo.y = bfr(v.y - bfu(h.y));
    lo.z = bfr(v.z - bfu(h.z)); lo.w = bfr(v.w - bfu(h.w));
    const int kt = d0 >> 5, lane = row | (((d0 >> 3) & 3) << 4), j = d0 & 7;
    *(ushort4*)&aF[0][kt*512 + lane*8 + j] = h;
    *(ushort4*)&aF[1][kt*512 + lane*8 + j] = lo;
  }
  __syncthreads();
  // ---- GEMM3 + residual -> x
  k4_gemm(acc, aF, wg + 2*65536, w, l64);
  #pragma unroll
  for (int nt = 0; nt < 4; ++nt) {
    const int cn = (w*4 + nt)*16 + col;
    #pragma unroll
    for (int r = 0; r < 4; ++r)
      x[(row0 + quad*4 + r)*256 + cn] = acc[nt][r] + mb2c[cn] + xtr[nt][r];
  }
}

// ---------------------------------------------------------------------------
// k5: s=sum_K x ; h=gelu(s@projT+pb) ; mu=h@muT+mb ; scale=softplus(h@spT+sb)
// ---------------------------------------------------------------------------
__global__ __launch_bounds__(256) void k5_head(
    const float* __restrict__ x, const float* __restrict__ wh,
    const float* __restrict__ bc, const int* __restrict__ flag,
    void* __restrict__ out)
{
  __shared__ float ss[256];
  __shared__ float hh[128];
  const int b = blockIdx.x, t = threadIdx.x;
  const int fl = *flag;
  float s = 0.f;
  for (int i = 0; i < 64; ++i) s += x[((b << 6) + i)*256 + t];
  ss[t] = s;
  __syncthreads();
  if (t < 128) {
    float acc = bc[3072 + t];
    const float* projT = wh;
    for (int d = 0; d < 256; ++d) acc = fmaf(ss[d], projT[d*128 + t], acc);
    hh[t] = gelu_e(acc);
  }
  __syncthreads();
  float v; int oidx;
  if (t < 128) {
    float acc = bc[3200 + t];
    const float* muT = wh + 32768;
    for (int c = 0; c < 128; ++c) acc = fmaf(hh[c], muT[c*128 + t], acc);
    v = acc; oidx = b*128 + t;
  } else {
    const int u = t - 128;
    float acc = bc[3328 + u];
    const float* spT = wh + 49152;
    for (int c = 0; c < 128; ++c) acc = fmaf(hh[c], spT[c*128 + u], acc);
    v = (acc > 20.f) ? acc : log1pf(__expf(acc));
    oidx = 4096 + b*128 + u;
  }
  if (fl) ((bf16*)out)[oidx] = __float2bfloat16(v);
  else    ((float*)out)[oidx] = v;
}

// ---------------------------------------------------------------------------
extern "C" void kernel_launch(void* const* d_in, const int* in_sizes, int n_in,
                              void* d_out, int out_size, void* d_ws, size_t ws_size,
                              hipStream_t stream)
{
  (void)in_sizes; (void)n_in; (void)out_size; (void)ws_size;
  float* ws    = (float*)d_ws;
  int*   flag  = (int*)ws;
  float* x     = ws + 16;                         // 524288
  float* kqpq  = x + 524288;                      // 2097152
  float* g     = kqpq + 2097152;                  // 524288
  float* attn  = g + 524288;                      // 131072
  unsigned short* wfb = (unsigned short*)(attn + 131072);   // 524288 bf16 = 262144 f
  unsigned short* w3b = wfb + 524288;             // 393216 bf16 = 196608 f
  float* wh    = (float*)(w3b + 393216);          // 65536
  float* bc    = wh + 65536;                      // 3456
  // total ~15.2 MB

  detect_kernel<<<dim3(1), dim3(256), 0, stream>>>(d_in[0], flag);
  prep_kernel<<<dim3(5903), dim3(256), 0, stream>>>(
      d_in[0], d_in[1], d_in[2], d_in[3], d_in[5], d_in[9], d_in[11],
      d_in[13], d_in[15], d_in[17],
      d_in[4], d_in[6], d_in[7], d_in[8], d_in[10], d_in[12],
      d_in[14], d_in[16], d_in[18],
      flag, x, wfb, w3b, wh, bc);
  for (int l = 0; l < NL; ++l) {
    k1_kqpq<<<dim3(256), dim3(256), 0, stream>>>(x, wfb, bc, kqpq, l);
    ks_scores<<<dim3(32), dim3(256), 0, stream>>>(kqpq, attn);
    k23_agg<<<dim3(512), dim3(512), 0, stream>>>(kqpq, attn, g);
    k4_mix<<<dim3(128), dim3(256), 0, stream>>>(g, w3b, bc, x, l);
  }
  k5_head<<<dim3(32), dim3(256), 0, stream>>>(x, wh, bc, flag, (void*)d_out);
}